// Round 1
// baseline (508.008 us; speedup 1.0000x reference)
//
#include <hip/hip_runtime.h>
#include <hip/hip_bf16.h>

typedef __attribute__((ext_vector_type(8))) __bf16 bf16x8;
typedef __attribute__((ext_vector_type(4))) float floatx4;
typedef __attribute__((ext_vector_type(8))) unsigned short ushort8;

namespace {
constexpr int kC  = 256;
constexpr int kNV = 1024 * 12;        // 12288
constexpr int kP  = 8 * kNV;          // 98304 positions
constexpr float kEps = 1e-5f;

// ws layout in float units (unchanged from previous version; params region now unused)
constexpr size_t OFF_PARAMS = 0;
constexpr size_t OFF_PART   = 2048;                      // 4 stages x 8 buckets x 512
constexpr size_t OFF_WB     = 2048 + 16384;              // packed bf16 weights
constexpr size_t OFF_XT     = OFF_WB + 81920;            // x transposed [P][256] bf16; stage4 overwrites in-place with x1
constexpr size_t OFF_Y1     = OFF_XT + (size_t)kP * 256 / 2;
constexpr size_t OFF_Y2     = OFF_Y1 + (size_t)kP * 64 / 2;   // [P][256] bf16 (also y4)
constexpr size_t OFF_Y3     = OFF_Y2 + (size_t)kP * 256 / 2;
} // namespace

__device__ __forceinline__ unsigned short f2bf(float f) {
    unsigned int u = __builtin_bit_cast(unsigned int, f);
    u += 0x7FFFu + ((u >> 16) & 1u);
    return (unsigned short)(u >> 16);
}
__device__ __forceinline__ float bf2f(unsigned short h) {
    unsigned int u = ((unsigned int)h) << 16;
    return __builtin_bit_cast(float, u);
}

// Pack the 4 weight matrices to bf16 in MFMA-fragment order:
// dst[base + (k/32)*(M*32) + m*32 + (k%32)]
__global__ void convw_kernel(const float* __restrict__ We, const float* __restrict__ Wa,
                             const float* __restrict__ Wo, const float* __restrict__ Wf,
                             unsigned short* __restrict__ dst)
{
    const int f = (blockIdx.x * 256 + threadIdx.x) * 4;
    const float* src; int off, M, K, base;
    if (f < 16384)      { src = We;            off = f;         M = 64;  K = 256; base = 0; }
    else if (f < 32768) { src = Wa + 512 * 64; off = f - 16384; M = 256; K = 64;  base = 16384; }
    else if (f < 98304) { src = Wo;            off = f - 32768; M = 256; K = 256; base = 32768; }
    else                { src = Wf;            off = f - 98304; M = 256; K = 256; base = 98304; }
    const int m = off / K, k = off - m * K;
    const float4 v = *(const float4*)&src[off];
    ushort4 o; o.x = f2bf(v.x); o.y = f2bf(v.y); o.z = f2bf(v.z); o.w = f2bf(v.w);
    *(ushort4*)&dst[base + (k >> 5) * (M * 32) + m * 32 + (k & 31)] = o;
}

// x [B,256,NV] fp32 channel-major -> xT [P][256] bf16 position-major
__global__ __launch_bounds__(256) void transpose_kernel(
    const float* __restrict__ x, unsigned short* __restrict__ xT)
{
    __shared__ float T[64][65];
    const int p0 = blockIdx.x * 64;
    const int c0 = blockIdx.y * 64;
    const int b  = p0 / kNV;
    const int q0 = p0 - b * kNV;
    const int t  = threadIdx.x;

    const int cl = t >> 2;
    const int pq = (t & 3) * 16;
    const float* src = &x[(size_t)(b * kC + c0 + cl) * kNV + q0 + pq];
    #pragma unroll
    for (int i = 0; i < 4; ++i) {
        const float4 v = *(const float4*)&src[i * 4];
        T[cl][pq + i * 4 + 0] = v.x;
        T[cl][pq + i * 4 + 1] = v.y;
        T[cl][pq + i * 4 + 2] = v.z;
        T[cl][pq + i * 4 + 3] = v.w;
    }
    __syncthreads();
    const int pr = t >> 2;
    const int cb = (t & 3) * 16;
    #pragma unroll
    for (int i = 0; i < 2; ++i) {
        ushort8 o;
        #pragma unroll
        for (int j = 0; j < 8; ++j) o[j] = f2bf(T[cb + i * 8 + j][pr]);
        *(ushort8*)&xT[(size_t)(p0 + pr) * 256 + c0 + cb + i * 8] = o;
    }
}

template<int MODE>
__device__ __forceinline__ ushort8 xform(ushort8 y8, ushort8 x8, float mp,
                                         const float* __restrict__ actA,
                                         const float* __restrict__ actB, int kk)
{
    if constexpr (MODE == 0) {
        return y8;
    } else {
        const float4 a0 = *(const float4*)&actA[kk];
        const float4 a1 = *(const float4*)&actA[kk + 4];
        const float4 b0 = *(const float4*)&actB[kk];
        const float4 b1 = *(const float4*)&actB[kk + 4];
        const float aa[8] = {a0.x, a0.y, a0.z, a0.w, a1.x, a1.y, a1.z, a1.w};
        const float bb[8] = {b0.x, b0.y, b0.z, b0.w, b1.x, b1.y, b1.z, b1.w};
        ushort8 o;
        #pragma unroll
        for (int j = 0; j < 8; ++j) {
            float v = bf2f(y8[j]);
            v = mp * fmaxf(fmaf(aa[j], v, bb[j]), 0.f);
            if constexpr (MODE == 2) v += bf2f(x8[j]);
            o[j] = f2bf(v);
        }
        return o;
    }
}

// A-stationary-ish GEMM. Block = 4 waves; wave owns BM/4 output channels.
// For small A slices (stages 1/2: NT*FM<=8) the wave's full-K A fragments live in
// registers. For the 256x256 stages they would cost 128 VGPRs/wave (capping
// occupancy at 2 waves/SIMD) -> instead re-load A fragments from L2 per slab with
// a 1-tile rotate (A is 128 KB, permanently L2-hot); frees ~96 regs so 3 blocks/CU fit.
// BN affine of the PREVIOUS stage is computed redundantly per block in the prologue
// from the `part` buckets (replaces the separate finalize_kernel launches).
// MODE 0: in raw bf16 [P][K]. MODE 1: in = mask*relu(a*y+b). MODE 2: MODE1 + XT
// residual, transformed value written back in-place to XT (becomes x1).
template<int BM, int K, int MODE, int MINW>
__global__ __launch_bounds__(256, MINW) void gemm_kernel(
    const unsigned short* __restrict__ Apk, const float* __restrict__ bias,
    const unsigned short* __restrict__ Yprev, unsigned short* __restrict__ XT,
    const float* __restrict__ mask,
    const float* __restrict__ pPrev, const float* __restrict__ gPrev,
    const float* __restrict__ btPrev,
    unsigned short* __restrict__ Yout, float* __restrict__ partial, int slabsPerBlock)
{
    constexpr int LD = 264;              // padded row stride (shorts)
    constexpr int NT = K / 32;
    constexpr int FM = BM / 64;          // 4 (BM=256) or 1 (BM=64)
    constexpr int FP = 2;                // 32 positions per slab
    constexpr int CH = K / 64;           // ushort8 chunks per thread per stream
    constexpr bool AREG = (NT * FM <= 8);
    __shared__ unsigned short Bs[2][32 * LD];
    __shared__ float Sst[2][256];
    __shared__ float ActA[256];
    __shared__ float ActB[256];

    const int tid  = threadIdx.x;
    const int w    = tid >> 6, lane = tid & 63, quad = lane >> 4, lt = lane & 15;
    const int mBase = w * 16 * FM;

    Sst[0][tid] = 0.f; Sst[1][tid] = 0.f;

    // ---- fold previous stage's BN into per-channel affine (replaces finalize_kernel) ----
    if constexpr (MODE != 0) {
        if (tid < K) {
            float s = 0.f, s2 = 0.f;
            #pragma unroll
            for (int k = 0; k < 8; ++k) {
                s  += pPrev[k * 512 + tid];
                s2 += pPrev[k * 512 + 256 + tid];
            }
            const float mu  = s * (1.f / kP);
            const float var = s2 * (1.f / kP) - mu * mu;
            const float A   = rsqrtf(var + kEps) * gPrev[tid];
            ActA[tid] = A;
            ActB[tid] = fmaf(-mu, A, btPrev[tid]);
        }
        __syncthreads();
    }

    const unsigned short* aBase = &Apk[(size_t)(mBase + lt) * 32 + quad * 8];

    // ---- A fragments in registers only when the slice is small (stages 1/2) ----
    ushort8 Areg[AREG ? NT : 1][FM];
    if constexpr (AREG) {
        #pragma unroll
        for (int t = 0; t < NT; ++t)
            #pragma unroll
            for (int fm = 0; fm < FM; ++fm)
                Areg[t][fm] = *(const ushort8*)&aBase[(size_t)(t * BM + fm * 16) * 32];
    }

    const int spb   = slabsPerBlock;
    const int slab0 = blockIdx.x * spb;

    // ---- prologue: stage slab 0 into Bs[0] ----
    {
        const int pBase = slab0 * 32;
        #pragma unroll
        for (int i = 0; i < CH; ++i) {
            const int c = tid + i * 256;
            const int p = c / (K / 8);
            const int kq = (c % (K / 8)) * 8;
            const ushort8 y8 = *(const ushort8*)&Yprev[(size_t)(pBase + p) * K + kq];
            ushort8 o;
            if constexpr (MODE == 0) o = y8;
            else {
                ushort8 x8{};
                if constexpr (MODE == 2) x8 = *(const ushort8*)&XT[(size_t)(pBase + p) * K + kq];
                o = xform<MODE>(y8, x8, mask[pBase + p], ActA, ActB, kq);
                if constexpr (MODE == 2) *(ushort8*)&XT[(size_t)(pBase + p) * K + kq] = o;
            }
            *(ushort8*)&Bs[0][p * LD + kq] = o;
        }
    }
    __syncthreads();

    for (int s = 0; s < spb; ++s) {
        const int pBase = (slab0 + s) * 32;
        const bool hasNext = (s + 1 < spb);

        // ---- prefetch next slab's streams into registers (latency covered by MFMAs) ----
        ushort8 py[CH];
        ushort8 px[(MODE == 2) ? CH : 1];
        if (hasNext) {
            const int pN = (slab0 + s + 1) * 32;
            #pragma unroll
            for (int i = 0; i < CH; ++i) {
                const int c = tid + i * 256;
                const int p = c / (K / 8);
                const int kq = (c % (K / 8)) * 8;
                py[i] = *(const ushort8*)&Yprev[(size_t)(pN + p) * K + kq];
                if constexpr (MODE == 2)
                    px[i] = *(const ushort8*)&XT[(size_t)(pN + p) * K + kq];
            }
        }

        // ---- MFMA over current slab: LDS B + (registers | L2-rotated) A ----
        floatx4 acc[FM][FP];
        #pragma unroll
        for (int fm = 0; fm < FM; ++fm)
            #pragma unroll
            for (int fp = 0; fp < FP; ++fp) acc[fm][fp] = (floatx4)0.f;

        const unsigned short* bs = &Bs[s & 1][0];

        ushort8 aCur[FM];
        if constexpr (!AREG) {
            #pragma unroll
            for (int fm = 0; fm < FM; ++fm)
                aCur[fm] = *(const ushort8*)&aBase[(size_t)(fm * 16) * 32];
        }

        #pragma unroll
        for (int t = 0; t < NT; ++t) {
            bf16x8 bF[FP];
            #pragma unroll
            for (int fp = 0; fp < FP; ++fp)
                bF[fp] = *(const bf16x8*)&bs[(fp * 16 + lt) * LD + t * 32 + quad * 8];
            ushort8 aNxt[FM];
            if constexpr (!AREG) {
                if (t + 1 < NT) {
                    #pragma unroll
                    for (int fm = 0; fm < FM; ++fm)
                        aNxt[fm] = *(const ushort8*)&aBase[(size_t)((t + 1) * BM + fm * 16) * 32];
                }
            }
            #pragma unroll
            for (int fm = 0; fm < FM; ++fm) {
                const bf16x8 aF = AREG ? __builtin_bit_cast(bf16x8, Areg[AREG ? t : 0][fm])
                                       : __builtin_bit_cast(bf16x8, aCur[fm]);
                #pragma unroll
                for (int fp = 0; fp < FP; ++fp)
                    acc[fm][fp] = __builtin_amdgcn_mfma_f32_16x16x32_bf16(aF, bF[fp], acc[fm][fp], 0, 0, 0);
            }
            if constexpr (!AREG) {
                if (t + 1 < NT) {
                    #pragma unroll
                    for (int fm = 0; fm < FM; ++fm) aCur[fm] = aNxt[fm];
                }
            }
        }

        // ---- epilogue: bias + mask, bf16 store, stats into LDS (owner lanes) ----
        float mpv[FP];
        #pragma unroll
        for (int fp = 0; fp < FP; ++fp) mpv[fp] = mask[pBase + fp * 16 + lt];

        float sS[FM][4], sQ[FM][4];
        #pragma unroll
        for (int fm = 0; fm < FM; ++fm)
            #pragma unroll
            for (int i = 0; i < 4; ++i) { sS[fm][i] = 0.f; sQ[fm][i] = 0.f; }

        #pragma unroll
        for (int fm = 0; fm < FM; ++fm) {
            const float4 bia = *(const float4*)&bias[mBase + fm * 16 + quad * 4];
            const float bi[4] = {bia.x, bia.y, bia.z, bia.w};
            #pragma unroll
            for (int fp = 0; fp < FP; ++fp) {
                const int pG = pBase + fp * 16 + lt;
                float vv[4];
                #pragma unroll
                for (int i = 0; i < 4; ++i) {
                    const float v = (acc[fm][fp][i] + bi[i]) * mpv[fp];
                    vv[i] = v; sS[fm][i] += v; sQ[fm][i] += v * v;
                }
                ushort4 o; o.x = f2bf(vv[0]); o.y = f2bf(vv[1]); o.z = f2bf(vv[2]); o.w = f2bf(vv[3]);
                *(ushort4*)&Yout[(size_t)pG * BM + mBase + fm * 16 + quad * 4] = o;
            }
        }
        #pragma unroll
        for (int fm = 0; fm < FM; ++fm)
            #pragma unroll
            for (int i = 0; i < 4; ++i) {
                #pragma unroll
                for (int off = 1; off < 16; off <<= 1) {
                    sS[fm][i] += __shfl_xor(sS[fm][i], off);
                    sQ[fm][i] += __shfl_xor(sQ[fm][i], off);
                }
            }
        if (lt == 0) {
            #pragma unroll
            for (int fm = 0; fm < FM; ++fm)
                #pragma unroll
                for (int i = 0; i < 4; ++i) {
                    const int ch = mBase + fm * 16 + quad * 4 + i;   // unique owner per ch
                    Sst[0][ch] += sS[fm][i];
                    Sst[1][ch] += sQ[fm][i];
                }
        }

        // ---- xform prefetched data, write other LDS buffer ----
        if (hasNext) {
            const int pN = (slab0 + s + 1) * 32;
            unsigned short* bn = &Bs[(s + 1) & 1][0];
            #pragma unroll
            for (int i = 0; i < CH; ++i) {
                const int c = tid + i * 256;
                const int p = c / (K / 8);
                const int kq = (c % (K / 8)) * 8;
                ushort8 o;
                if constexpr (MODE == 0) o = py[i];
                else {
                    ushort8 x8{};
                    if constexpr (MODE == 2) x8 = px[i];
                    o = xform<MODE>(py[i], x8, mask[pN + p], ActA, ActB, kq);
                    if constexpr (MODE == 2) *(ushort8*)&XT[(size_t)(pN + p) * K + kq] = o;
                }
                *(ushort8*)&bn[p * LD + kq] = o;
            }
        }
        __syncthreads();
    }

    // ---- flush block stats (one bucketed atomic pass) ----
    if (tid < BM) {
        float* pb = partial + (size_t)(blockIdx.x & 7) * 512;
        atomicAdd(&pb[tid], Sst[0][tid]);
        atomicAdd(&pb[256 + tid], Sst[1][tid]);
    }
}

// out[c][q] = x1 + act4(y4); x1,y4 are [P][256] bf16 -> transpose via LDS.
// act4 affine computed in-prologue from stage-4 partials (finalize folded in).
__global__ __launch_bounds__(256) void final_kernel(
    const unsigned short* __restrict__ x1, const unsigned short* __restrict__ y4,
    const float* __restrict__ part4, const float* __restrict__ g4,
    const float* __restrict__ bt4,
    const float* __restrict__ mask, float* __restrict__ out)
{
    constexpr int TL = 264;
    __shared__ unsigned short TX[32 * TL];
    __shared__ unsigned short T4[32 * TL];
    __shared__ float PA[256];
    __shared__ float PB[256];
    const int p0 = blockIdx.x * 32;
    const int b  = p0 / kNV;
    const int q0 = p0 - b * kNV;

    {
        const int m = threadIdx.x;
        float s = 0.f, s2 = 0.f;
        #pragma unroll
        for (int k = 0; k < 8; ++k) { s += part4[k * 512 + m]; s2 += part4[k * 512 + 256 + m]; }
        const float mu  = s * (1.f / kP);
        const float var = s2 * (1.f / kP) - mu * mu;
        const float A   = rsqrtf(var + kEps) * g4[m];
        PA[m] = A;
        PB[m] = fmaf(-mu, A, bt4[m]);
    }

    #pragma unroll
    for (int i = 0; i < 4; ++i) {
        const int idx = threadIdx.x + i * 256;
        const int p = idx >> 5, c0 = (idx & 31) * 8;
        *(ushort8*)&TX[p * TL + c0] = *(const ushort8*)&x1[(size_t)(p0 + p) * 256 + c0];
        *(ushort8*)&T4[p * TL + c0] = *(const ushort8*)&y4[(size_t)(p0 + p) * 256 + c0];
    }
    __syncthreads();

    const int qv = (threadIdx.x & 15) * 2;
    const int cb = threadIdx.x >> 4;
    const float m0v = mask[p0 + qv], m1v = mask[p0 + qv + 1];
    #pragma unroll
    for (int j = 0; j < 16; ++j) {
        const int c = cb + j * 16;
        const float a4 = PA[c], b4 = PB[c];
        const size_t ro = (size_t)(b * kC + c) * kNV + q0 + qv;
        float2 o;
        o.x = bf2f(TX[qv * TL + c])       + m0v * fmaxf(fmaf(a4, bf2f(T4[qv * TL + c]), b4), 0.f);
        o.y = bf2f(TX[(qv + 1) * TL + c]) + m1v * fmaxf(fmaf(a4, bf2f(T4[(qv + 1) * TL + c]), b4), 0.f);
        *(float2*)&out[ro] = o;
    }
}

extern "C" void kernel_launch(void* const* d_in, const int* in_sizes, int n_in,
                              void* d_out, int out_size, void* d_ws, size_t ws_size,
                              hipStream_t stream)
{
    const float* x    = (const float*)d_in[0];
    const float* mask = (const float*)d_in[1];
    const float* We   = (const float*)d_in[2];
    const float* be   = (const float*)d_in[3];
    const float* ge   = (const float*)d_in[4];
    const float* bne  = (const float*)d_in[5];
    const float* Wa   = (const float*)d_in[6];
    const float* ba   = (const float*)d_in[7];
    const float* ga   = (const float*)d_in[8];
    const float* bna  = (const float*)d_in[9];
    const float* Wo   = (const float*)d_in[10];
    const float* bo   = (const float*)d_in[11];
    const float* go   = (const float*)d_in[12];
    const float* bno  = (const float*)d_in[13];
    const float* Wf   = (const float*)d_in[14];
    const float* bf   = (const float*)d_in[15];
    const float* gf   = (const float*)d_in[16];
    const float* bnf  = (const float*)d_in[17];
    float* out = (float*)d_out;
    float* ws  = (float*)d_ws;

    float* part = ws + OFF_PART;
    unsigned short* Wb = (unsigned short*)(ws + OFF_WB);
    unsigned short* xT = (unsigned short*)(ws + OFF_XT);   // becomes x1 after stage 4
    unsigned short* y1 = (unsigned short*)(ws + OFF_Y1);
    unsigned short* y2 = (unsigned short*)(ws + OFF_Y2);   // later reused as y4
    unsigned short* y3 = (unsigned short*)(ws + OFF_Y3);

    hipMemsetAsync(part, 0, 16384 * sizeof(float), stream);
    convw_kernel<<<160, 256, 0, stream>>>(We, Wa, Wo, Wf, Wb);
    transpose_kernel<<<dim3(kP / 64, 4), 256, 0, stream>>>(x, xT);

    const dim3 blk(256);
    // stages 1/2: small A slices -> 4 blocks/CU; stages 3/4: A re-streamed from L2 -> 3 blocks/CU
    const int SPB12 = kP / 32 / 1024;   // 3
    const int SPB34 = kP / 32 / 768;    // 4

    // stage 1: y1 = mask*(We @ x + be)  [P][64]
    gemm_kernel<64, 256, 0, 4><<<1024, blk, 0, stream>>>(
        Wb, be, xT, nullptr, mask, nullptr, nullptr, nullptr, y1, part, SPB12);

    // stage 2: y2 = mask*(Wa_v @ act1(y1) + ba_v)  [P][256]   (act1 folded in-prologue)
    gemm_kernel<256, 64, 1, 4><<<1024, blk, 0, stream>>>(
        Wb + 16384, ba + 512, y1, nullptr, mask, part, ge, bne, y2, part + 4096, SPB12);

    // stage 3: y3 = mask*(Wo @ act2(y2) + bo)
    gemm_kernel<256, 256, 1, 3><<<768, blk, 0, stream>>>(
        Wb + 32768, bo, y2, nullptr, mask, part + 4096, ga + 512, bna + 512, y3, part + 8192, SPB34);

    // stage 4: y4 = mask*(Wf @ x1 + bf), x1 = x + act3(y3) written in-place into xT
    gemm_kernel<256, 256, 2, 3><<<768, blk, 0, stream>>>(
        Wb + 98304, bf, y3, xT, mask, part + 8192, go, bno, y2, part + 12288, SPB34);

    // final: out = x1 + act4(y4)   (act4 folded in-prologue)
    final_kernel<<<kP / 32, blk, 0, stream>>>(
        xT, y2, part + 12288, gf, bnf, mask, out);
}

// Round 2
// 384.963 us; speedup vs baseline: 1.3196x; 1.3196x over previous
//
#include <hip/hip_runtime.h>
#include <hip/hip_bf16.h>

typedef __attribute__((ext_vector_type(8))) __bf16 bf16x8;
typedef __attribute__((ext_vector_type(4))) float floatx4;
typedef __attribute__((ext_vector_type(8))) unsigned short ushort8;

namespace {
constexpr int kC  = 256;
constexpr int kNV = 1024 * 12;        // 12288
constexpr int kP  = 8 * kNV;          // 98304 positions
constexpr float kEps = 1e-5f;

// ws layout in float units
constexpr size_t OFF_PART   = 2048;                      // 4 stages x 8 buckets x 512
constexpr size_t OFF_WB     = 2048 + 16384;              // packed bf16 weights
constexpr size_t OFF_XT     = OFF_WB + 81920;            // x transposed [P][256] bf16 (stays pristine now)
constexpr size_t OFF_Y1     = OFF_XT + (size_t)kP * 256 / 2;
constexpr size_t OFF_Y2     = OFF_Y1 + (size_t)kP * 64 / 2;   // [P][256] bf16 (also y4)
constexpr size_t OFF_Y3     = OFF_Y2 + (size_t)kP * 256 / 2;
} // namespace

__device__ __forceinline__ unsigned short f2bf(float f) {
    unsigned int u = __builtin_bit_cast(unsigned int, f);
    u += 0x7FFFu + ((u >> 16) & 1u);
    return (unsigned short)(u >> 16);
}
__device__ __forceinline__ float bf2f(unsigned short h) {
    unsigned int u = ((unsigned int)h) << 16;
    return __builtin_bit_cast(float, u);
}

// Pack the 4 weight matrices to bf16 in MFMA-fragment order:
// dst[base + (k/32)*(M*32) + m*32 + (k%32)]
__global__ void convw_kernel(const float* __restrict__ We, const float* __restrict__ Wa,
                             const float* __restrict__ Wo, const float* __restrict__ Wf,
                             unsigned short* __restrict__ dst)
{
    const int f = (blockIdx.x * 256 + threadIdx.x) * 4;
    const float* src; int off, M, K, base;
    if (f < 16384)      { src = We;            off = f;         M = 64;  K = 256; base = 0; }
    else if (f < 32768) { src = Wa + 512 * 64; off = f - 16384; M = 256; K = 64;  base = 16384; }
    else if (f < 98304) { src = Wo;            off = f - 32768; M = 256; K = 256; base = 32768; }
    else                { src = Wf;            off = f - 98304; M = 256; K = 256; base = 98304; }
    const int m = off / K, k = off - m * K;
    const float4 v = *(const float4*)&src[off];
    ushort4 o; o.x = f2bf(v.x); o.y = f2bf(v.y); o.z = f2bf(v.z); o.w = f2bf(v.w);
    *(ushort4*)&dst[base + (k >> 5) * (M * 32) + m * 32 + (k & 31)] = o;
}

// x [B,256,NV] fp32 channel-major -> xT [P][256] bf16 position-major
__global__ __launch_bounds__(256) void transpose_kernel(
    const float* __restrict__ x, unsigned short* __restrict__ xT)
{
    __shared__ float T[64][65];
    const int p0 = blockIdx.x * 64;
    const int c0 = blockIdx.y * 64;
    const int b  = p0 / kNV;
    const int q0 = p0 - b * kNV;
    const int t  = threadIdx.x;

    const int cl = t >> 2;
    const int pq = (t & 3) * 16;
    const float* src = &x[(size_t)(b * kC + c0 + cl) * kNV + q0 + pq];
    #pragma unroll
    for (int i = 0; i < 4; ++i) {
        const float4 v = *(const float4*)&src[i * 4];
        T[cl][pq + i * 4 + 0] = v.x;
        T[cl][pq + i * 4 + 1] = v.y;
        T[cl][pq + i * 4 + 2] = v.z;
        T[cl][pq + i * 4 + 3] = v.w;
    }
    __syncthreads();
    const int pr = t >> 2;
    const int cb = (t & 3) * 16;
    #pragma unroll
    for (int i = 0; i < 2; ++i) {
        ushort8 o;
        #pragma unroll
        for (int j = 0; j < 8; ++j) o[j] = f2bf(T[cb + i * 8 + j][pr]);
        *(ushort8*)&xT[(size_t)(p0 + pr) * 256 + c0 + cb + i * 8] = o;
    }
}

template<int MODE>
__device__ __forceinline__ ushort8 xform(ushort8 y8, ushort8 x8, float mp,
                                         const float* __restrict__ actA,
                                         const float* __restrict__ actB, int kk)
{
    if constexpr (MODE == 0) {
        return y8;
    } else {
        const float4 a0 = *(const float4*)&actA[kk];
        const float4 a1 = *(const float4*)&actA[kk + 4];
        const float4 b0 = *(const float4*)&actB[kk];
        const float4 b1 = *(const float4*)&actB[kk + 4];
        const float aa[8] = {a0.x, a0.y, a0.z, a0.w, a1.x, a1.y, a1.z, a1.w};
        const float bb[8] = {b0.x, b0.y, b0.z, b0.w, b1.x, b1.y, b1.z, b1.w};
        ushort8 o;
        #pragma unroll
        for (int j = 0; j < 8; ++j) {
            float v = bf2f(y8[j]);
            v = mp * fmaxf(fmaf(aa[j], v, bb[j]), 0.f);
            if constexpr (MODE == 2) v += bf2f(x8[j]);
            o[j] = f2bf(v);
        }
        return o;
    }
}

// A-stationary GEMM. Block = 4 waves; wave owns BM/4 output channels with full-K A
// fragments in REGISTERS (loaded once, L2-hot). B streams as 32-position slabs through
// a double-buffered LDS tile; one barrier per slab.
// HALVES=2: two sibling blocks split the MTOT output channels (BM=MTOT/2 each) for the
// same slab range; XCD-pairing swizzle co-locates siblings on one XCD so the shared
// B-stream is read once from HBM, second read hits that XCD's L2. This halves per-wave
// A-register cost (64 vs 128 VGPR) -> 3 blocks/CU instead of 2.
// BN affine of the PREVIOUS stage is computed per block in the prologue from the
// `part` buckets (finalize folded in).
// MODE 0: B = raw bf16. MODE 1: B = mask*relu(a*y+b). MODE 2: MODE1 + XT residual
// (XT read-only; x1 is NOT materialized -> no sibling write race).
template<int BM, int MTOT, int K, int MODE, int HALVES, int MINW>
__global__ __launch_bounds__(256, MINW) void gemm_kernel(
    const unsigned short* __restrict__ Apk, const float* __restrict__ bias,
    const unsigned short* __restrict__ Yprev, const unsigned short* __restrict__ XT,
    const float* __restrict__ mask,
    const float* __restrict__ pPrev, const float* __restrict__ gPrev,
    const float* __restrict__ btPrev,
    unsigned short* __restrict__ Yout, float* __restrict__ partial, int slabsPerBlock)
{
    constexpr int LD = 264;              // padded row stride (shorts): 2-way banks max
    constexpr int NT = K / 32;
    constexpr int FM = BM / 64;          // channels-per-wave / 16
    constexpr int FP = 2;                // 32 positions per slab
    constexpr int CH = K / 64;           // ushort8 chunks per thread per stream
    __shared__ unsigned short Bs[2][32 * LD];
    __shared__ float Sst[2][256];
    __shared__ float ActA[256];
    __shared__ float ActB[256];

    const int tid  = threadIdx.x;
    const int w    = tid >> 6, lane = tid & 63, quad = lane >> 4, lt = lane & 15;
    const int mBase = w * 16 * FM;

    Sst[0][tid] = 0.f; Sst[1][tid] = 0.f;

    // ---- block -> (pair, half) mapping. Round-robin dispatch puts bid%8 on XCD bid%8;
    // siblings (half 0/1 of a pair) are 8 apart in bid -> same XCD, adjacent in time.
    int pairId, half;
    if constexpr (HALVES == 2) {
        const int x = blockIdx.x & 7;
        const int s = blockIdx.x >> 3;
        half   = s & 1;
        pairId = x * (int)(gridDim.x >> 4) + (s >> 1);
    } else {
        pairId = blockIdx.x; half = 0;
    }
    const int chOff = half * BM;
    const int slab0 = pairId * slabsPerBlock;

    // ---- fold previous stage's BN into per-channel affine (replaces finalize_kernel) ----
    if constexpr (MODE != 0) {
        if (tid < K) {
            float s = 0.f, s2 = 0.f;
            #pragma unroll
            for (int k = 0; k < 8; ++k) {
                s  += pPrev[k * 512 + tid];
                s2 += pPrev[k * 512 + 256 + tid];
            }
            const float mu  = s * (1.f / kP);
            const float var = s2 * (1.f / kP) - mu * mu;
            const float A   = rsqrtf(var + kEps) * gPrev[tid];
            ActA[tid] = A;
            ActB[tid] = fmaf(-mu, A, btPrev[tid]);
        }
        __syncthreads();
    }

    // ---- A fragments: full K for this block's channel slice, in registers ----
    ushort8 Areg[NT][FM];
    #pragma unroll
    for (int t = 0; t < NT; ++t)
        #pragma unroll
        for (int fm = 0; fm < FM; ++fm)
            Areg[t][fm] = *(const ushort8*)&Apk[(size_t)(t * MTOT + chOff + mBase + fm * 16 + lt) * 32 + quad * 8];

    const int spb = slabsPerBlock;

    // ---- prologue: stage slab 0 into Bs[0] ----
    {
        const int pBase = slab0 * 32;
        #pragma unroll
        for (int i = 0; i < CH; ++i) {
            const int c = tid + i * 256;
            const int p = c / (K / 8);
            const int kq = (c % (K / 8)) * 8;
            const ushort8 y8 = *(const ushort8*)&Yprev[(size_t)(pBase + p) * K + kq];
            ushort8 o;
            if constexpr (MODE == 0) o = y8;
            else {
                ushort8 x8{};
                if constexpr (MODE == 2) x8 = *(const ushort8*)&XT[(size_t)(pBase + p) * K + kq];
                o = xform<MODE>(y8, x8, mask[pBase + p], ActA, ActB, kq);
            }
            *(ushort8*)&Bs[0][p * LD + kq] = o;
        }
    }
    __syncthreads();

    for (int s = 0; s < spb; ++s) {
        const int pBase = (slab0 + s) * 32;
        const bool hasNext = (s + 1 < spb);

        // ---- prefetch next slab's streams into registers (latency covered by MFMAs) ----
        ushort8 py[CH];
        ushort8 px[(MODE == 2) ? CH : 1];
        if (hasNext) {
            const int pN = (slab0 + s + 1) * 32;
            #pragma unroll
            for (int i = 0; i < CH; ++i) {
                const int c = tid + i * 256;
                const int p = c / (K / 8);
                const int kq = (c % (K / 8)) * 8;
                py[i] = *(const ushort8*)&Yprev[(size_t)(pN + p) * K + kq];
                if constexpr (MODE == 2)
                    px[i] = *(const ushort8*)&XT[(size_t)(pN + p) * K + kq];
            }
        }

        // ---- MFMA over current slab: LDS-only inner loop ----
        floatx4 acc[FM][FP];
        #pragma unroll
        for (int fm = 0; fm < FM; ++fm)
            #pragma unroll
            for (int fp = 0; fp < FP; ++fp) acc[fm][fp] = (floatx4)0.f;

        const unsigned short* bs = &Bs[s & 1][0];
        #pragma unroll
        for (int t = 0; t < NT; ++t) {
            bf16x8 bF[FP];
            #pragma unroll
            for (int fp = 0; fp < FP; ++fp)
                bF[fp] = *(const bf16x8*)&bs[(fp * 16 + lt) * LD + t * 32 + quad * 8];
            #pragma unroll
            for (int fm = 0; fm < FM; ++fm) {
                const bf16x8 aF = __builtin_bit_cast(bf16x8, Areg[t][fm]);
                #pragma unroll
                for (int fp = 0; fp < FP; ++fp)
                    acc[fm][fp] = __builtin_amdgcn_mfma_f32_16x16x32_bf16(aF, bF[fp], acc[fm][fp], 0, 0, 0);
            }
        }

        // ---- epilogue: bias + mask, bf16 store, stats into LDS (owner lanes) ----
        float mpv[FP];
        #pragma unroll
        for (int fp = 0; fp < FP; ++fp) mpv[fp] = mask[pBase + fp * 16 + lt];

        float sS[FM][4], sQ[FM][4];
        #pragma unroll
        for (int fm = 0; fm < FM; ++fm)
            #pragma unroll
            for (int i = 0; i < 4; ++i) { sS[fm][i] = 0.f; sQ[fm][i] = 0.f; }

        #pragma unroll
        for (int fm = 0; fm < FM; ++fm) {
            const float4 bia = *(const float4*)&bias[chOff + mBase + fm * 16 + quad * 4];
            const float bi[4] = {bia.x, bia.y, bia.z, bia.w};
            #pragma unroll
            for (int fp = 0; fp < FP; ++fp) {
                const int pG = pBase + fp * 16 + lt;
                float vv[4];
                #pragma unroll
                for (int i = 0; i < 4; ++i) {
                    const float v = (acc[fm][fp][i] + bi[i]) * mpv[fp];
                    vv[i] = v; sS[fm][i] += v; sQ[fm][i] += v * v;
                }
                ushort4 o; o.x = f2bf(vv[0]); o.y = f2bf(vv[1]); o.z = f2bf(vv[2]); o.w = f2bf(vv[3]);
                *(ushort4*)&Yout[(size_t)pG * MTOT + chOff + mBase + fm * 16 + quad * 4] = o;
            }
        }
        #pragma unroll
        for (int fm = 0; fm < FM; ++fm)
            #pragma unroll
            for (int i = 0; i < 4; ++i) {
                #pragma unroll
                for (int off = 1; off < 16; off <<= 1) {
                    sS[fm][i] += __shfl_xor(sS[fm][i], off);
                    sQ[fm][i] += __shfl_xor(sQ[fm][i], off);
                }
            }
        if (lt == 0) {
            #pragma unroll
            for (int fm = 0; fm < FM; ++fm)
                #pragma unroll
                for (int i = 0; i < 4; ++i) {
                    const int ch = mBase + fm * 16 + quad * 4 + i;   // unique owner per local ch
                    Sst[0][ch] += sS[fm][i];
                    Sst[1][ch] += sQ[fm][i];
                }
        }

        // ---- xform prefetched data, write other LDS buffer ----
        if (hasNext) {
            const int pN = (slab0 + s + 1) * 32;
            unsigned short* bn = &Bs[(s + 1) & 1][0];
            #pragma unroll
            for (int i = 0; i < CH; ++i) {
                const int c = tid + i * 256;
                const int p = c / (K / 8);
                const int kq = (c % (K / 8)) * 8;
                ushort8 o;
                if constexpr (MODE == 0) o = py[i];
                else {
                    ushort8 x8{};
                    if constexpr (MODE == 2) x8 = px[i];
                    o = xform<MODE>(py[i], x8, mask[pN + p], ActA, ActB, kq);
                }
                *(ushort8*)&bn[p * LD + kq] = o;
            }
        }
        __syncthreads();
    }

    // ---- flush block stats (one bucketed atomic pass) ----
    if (tid < BM) {
        float* pb = partial + (size_t)(blockIdx.x & 7) * 512;
        atomicAdd(&pb[chOff + tid], Sst[0][tid]);
        atomicAdd(&pb[256 + chOff + tid], Sst[1][tid]);
    }
}

// out[c][q] = x1 + act4(y4), with x1 = x + act3(y3) recomputed on the fly
// (x1 is never materialized; XT stays pristine). Transpose via LDS.
// Both act3 and act4 affines computed in-prologue from the part buckets.
__global__ __launch_bounds__(256) void final_kernel(
    const unsigned short* __restrict__ xT, const unsigned short* __restrict__ y3,
    const unsigned short* __restrict__ y4,
    const float* __restrict__ p3, const float* __restrict__ g3, const float* __restrict__ bt3,
    const float* __restrict__ p4, const float* __restrict__ g4, const float* __restrict__ bt4,
    const float* __restrict__ mask, float* __restrict__ out)
{
    constexpr int TL = 264;
    __shared__ unsigned short TX[32 * TL];   // x1 (bf16)
    __shared__ unsigned short T4[32 * TL];   // y4 raw
    __shared__ float PA3[256], PB3[256], PA4[256], PB4[256];
    const int p0 = blockIdx.x * 32;
    const int b  = p0 / kNV;
    const int q0 = p0 - b * kNV;

    {
        const int m = threadIdx.x;
        float s3 = 0.f, q3 = 0.f, s4 = 0.f, q4 = 0.f;
        #pragma unroll
        for (int k = 0; k < 8; ++k) {
            s3 += p3[k * 512 + m]; q3 += p3[k * 512 + 256 + m];
            s4 += p4[k * 512 + m]; q4 += p4[k * 512 + 256 + m];
        }
        const float mu3 = s3 * (1.f / kP);
        const float A3  = rsqrtf(q3 * (1.f / kP) - mu3 * mu3 + kEps) * g3[m];
        PA3[m] = A3; PB3[m] = fmaf(-mu3, A3, bt3[m]);
        const float mu4 = s4 * (1.f / kP);
        const float A4  = rsqrtf(q4 * (1.f / kP) - mu4 * mu4 + kEps) * g4[m];
        PA4[m] = A4; PB4[m] = fmaf(-mu4, A4, bt4[m]);
    }
    __syncthreads();

    #pragma unroll
    for (int i = 0; i < 4; ++i) {
        const int idx = threadIdx.x + i * 256;
        const int p = idx >> 5, c0 = (idx & 31) * 8;
        const ushort8 x8  = *(const ushort8*)&xT[(size_t)(p0 + p) * 256 + c0];
        const ushort8 y38 = *(const ushort8*)&y3[(size_t)(p0 + p) * 256 + c0];
        const ushort8 y48 = *(const ushort8*)&y4[(size_t)(p0 + p) * 256 + c0];
        const float mp = mask[p0 + p];
        ushort8 o;
        #pragma unroll
        for (int j = 0; j < 8; ++j) {
            const int c = c0 + j;
            const float x1 = bf2f(x8[j]) + mp * fmaxf(fmaf(PA3[c], bf2f(y38[j]), PB3[c]), 0.f);
            o[j] = f2bf(x1);
        }
        *(ushort8*)&TX[p * TL + c0] = o;
        *(ushort8*)&T4[p * TL + c0] = y48;
    }
    __syncthreads();

    const int qv = (threadIdx.x & 15) * 2;
    const int cb = threadIdx.x >> 4;
    const float m0v = mask[p0 + qv], m1v = mask[p0 + qv + 1];
    #pragma unroll
    for (int j = 0; j < 16; ++j) {
        const int c = cb + j * 16;
        const float a4 = PA4[c], b4 = PB4[c];
        const size_t ro = (size_t)(b * kC + c) * kNV + q0 + qv;
        float2 o;
        o.x = bf2f(TX[qv * TL + c])       + m0v * fmaxf(fmaf(a4, bf2f(T4[qv * TL + c]), b4), 0.f);
        o.y = bf2f(TX[(qv + 1) * TL + c]) + m1v * fmaxf(fmaf(a4, bf2f(T4[(qv + 1) * TL + c]), b4), 0.f);
        *(float2*)&out[ro] = o;
    }
}

extern "C" void kernel_launch(void* const* d_in, const int* in_sizes, int n_in,
                              void* d_out, int out_size, void* d_ws, size_t ws_size,
                              hipStream_t stream)
{
    const float* x    = (const float*)d_in[0];
    const float* mask = (const float*)d_in[1];
    const float* We   = (const float*)d_in[2];
    const float* be   = (const float*)d_in[3];
    const float* ge   = (const float*)d_in[4];
    const float* bne  = (const float*)d_in[5];
    const float* Wa   = (const float*)d_in[6];
    const float* ba   = (const float*)d_in[7];
    const float* ga   = (const float*)d_in[8];
    const float* bna  = (const float*)d_in[9];
    const float* Wo   = (const float*)d_in[10];
    const float* bo   = (const float*)d_in[11];
    const float* go   = (const float*)d_in[12];
    const float* bno  = (const float*)d_in[13];
    const float* Wf   = (const float*)d_in[14];
    const float* bf   = (const float*)d_in[15];
    const float* gf   = (const float*)d_in[16];
    const float* bnf  = (const float*)d_in[17];
    float* out = (float*)d_out;
    float* ws  = (float*)d_ws;

    float* part = ws + OFF_PART;
    unsigned short* Wb = (unsigned short*)(ws + OFF_WB);
    unsigned short* xT = (unsigned short*)(ws + OFF_XT);
    unsigned short* y1 = (unsigned short*)(ws + OFF_Y1);
    unsigned short* y2 = (unsigned short*)(ws + OFF_Y2);   // later reused as y4
    unsigned short* y3 = (unsigned short*)(ws + OFF_Y3);

    hipMemsetAsync(part, 0, 16384 * sizeof(float), stream);
    convw_kernel<<<160, 256, 0, stream>>>(We, Wa, Wo, Wf, Wb);
    transpose_kernel<<<dim3(kP / 64, 4), 256, 0, stream>>>(x, xT);

    const dim3 blk(256);

    // stage 1: y1 = mask*(We @ x + be)  [P][64]   A-regs=32 VGPR -> 4 blocks/CU
    gemm_kernel<64, 64, 256, 0, 1, 4><<<1024, blk, 0, stream>>>(
        Wb, be, xT, nullptr, mask, nullptr, nullptr, nullptr, y1, part, 3);

    // stage 2: y2 = mask*(Wa_v @ act1(y1) + ba_v)  [P][256]   A-regs=32 VGPR
    gemm_kernel<256, 256, 64, 1, 1, 4><<<1024, blk, 0, stream>>>(
        Wb + 16384, ba + 512, y1, nullptr, mask, part, ge, bne, y2, part + 4096, 3);

    // stage 3: y3 = mask*(Wo @ act2(y2) + bo)   half-channel sibling blocks, A-regs=64
    gemm_kernel<128, 256, 256, 1, 2, 3><<<768, blk, 0, stream>>>(
        Wb + 32768, bo, y2, nullptr, mask, part + 4096, ga + 512, bna + 512, y3, part + 8192, 8);

    // stage 4: y4 = mask*(Wf @ (x + act3(y3)) + bf)   XT read-only (no x1 writeback)
    gemm_kernel<128, 256, 256, 2, 2, 3><<<768, blk, 0, stream>>>(
        Wb + 98304, bf, y3, xT, mask, part + 8192, go, bno, y2, part + 12288, 8);

    // final: out = (x + act3(y3)) + act4(y4)
    final_kernel<<<kP / 32, blk, 0, stream>>>(
        xT, y3, y2, part + 8192, go, bno, part + 12288, gf, bnf, mask, out);
}